// Round 7
// baseline (200.499 us; speedup 1.0000x reference)
//
#include <hip/hip_runtime.h>
#include <hip/hip_bf16.h>

#define D_MODEL 1024
#define D_HEAD  64
#define T_SEQ   4096
#define NB      4
#define NROWS   (NB * T_SEQ)      // 16384
#define SPLIT   8

typedef float f32x4 __attribute__((ext_vector_type(4)));
typedef __bf16 bf16x8 __attribute__((ext_vector_type(8)));
typedef unsigned short u16;
typedef unsigned u32x2 __attribute__((ext_vector_type(2)));
typedef unsigned u32x4 __attribute__((ext_vector_type(4)));

__device__ inline unsigned pk_bf16(float a, float b) {
    unsigned ua = __builtin_bit_cast(unsigned, a);
    unsigned ub = __builtin_bit_cast(unsigned, b);
    ua = (ua + 0x7FFFu + ((ua >> 16) & 1u)) >> 16;   // RNE
    ub = (ub + 0x7FFFu + ((ub >> 16) & 1u)) >> 16;
    return ua | (ub << 16);
}
__device__ inline u16 bf16r(float a) {
    unsigned ua = __builtin_bit_cast(unsigned, a);
    return (u16)((ua + 0x7FFFu + ((ua >> 16) & 1u)) >> 16);
}

// ---------------- W pre-pack: Wpk[kb][n][j] = W_sel[(kb*8+j)*64 + col], bf16 ----------------
__global__ __launch_bounds__(256) void packw_kernel(
    const float* __restrict__ Wq, const float* __restrict__ Wk,
    const float* __restrict__ Wv, unsigned* __restrict__ Wpk)
{
    const int id = blockIdx.x * 256 + threadIdx.x;   // 0..24575
    const int kb = id / 192;
    const int n  = id - kb * 192;
    const int sel = n >> 6, col = n & 63;
    const float* W = sel == 0 ? Wq : (sel == 1 ? Wk : Wv);
    float f[8];
#pragma unroll
    for (int j = 0; j < 8; ++j) f[j] = W[(kb * 8 + j) * 64 + col];
    uint4 o;
    o.x = pk_bf16(f[0], f[1]); o.y = pk_bf16(f[2], f[3]);
    o.z = pk_bf16(f[4], f[5]); o.w = pk_bf16(f[6], f[7]);
    *(uint4*)(Wpk + (size_t)id * 4) = o;
}

// ---------------- QKV projection: streaming LDS-staged GEMM, BK=128 dbuf --------------------
// R17: x loads nontemporal (read-once, 64 MB — keep it out of L2 so attn's K/V stay hot).
__global__ __launch_bounds__(256) void qkv_kernel(
    const float* __restrict__ x, const unsigned* __restrict__ Wpk,
    u16* __restrict__ Qbf, u16* __restrict__ Kbf, u16* __restrict__ Vt)
{
    __shared__ __align__(16) unsigned Xs[2][32 * 68];   // 32 rows x 128 bf16 (stride 136)
    __shared__ __align__(16) u16 Vbuf[64 * 32];         // V^T bounce: [dim 64][tpos 32]

    const int tid  = threadIdx.x;
    const int w    = tid >> 6;
    const int lane = tid & 63;
    const int nl   = lane & 15;
    const int quad = lane >> 4;
    const long row0 = (long)blockIdx.x * 32;

    const int srow = tid >> 5;          // staging: base row 0..7 (+8 per pass)
    const int scol = (tid & 31) * 4;    // staging col 0..124

    f32x4 acc[2][3] = {};

    f32x4 nx[4];
#pragma unroll
    for (int p = 0; p < 4; ++p)
        nx[p] = __builtin_nontemporal_load(
            (const f32x4*)(x + (row0 + p * 8 + srow) * D_MODEL + scol));

    for (int ch = 0; ch < 8; ++ch) {
        const int buf = ch & 1;
#pragma unroll
        for (int p = 0; p < 4; ++p) {
            uint2 pk2;
            pk2.x = pk_bf16(nx[p][0], nx[p][1]);
            pk2.y = pk_bf16(nx[p][2], nx[p][3]);
            *(uint2*)&Xs[buf][(p * 8 + srow) * 68 + (scol >> 1)] = pk2;
        }
        __syncthreads();
        if (ch < 7) {
#pragma unroll
            for (int p = 0; p < 4; ++p)
                nx[p] = __builtin_nontemporal_load(
                    (const f32x4*)(x + (row0 + p * 8 + srow) * D_MODEL
                                     + (ch + 1) * 128 + scol));
        }
#pragma unroll
        for (int kk = 0; kk < 4; ++kk) {
            const bf16x8 a0 = __builtin_bit_cast(bf16x8,
                *(const uint4*)&Xs[buf][nl * 68 + kk * 16 + quad * 4]);
            const bf16x8 a1 = __builtin_bit_cast(bf16x8,
                *(const uint4*)&Xs[buf][(16 + nl) * 68 + kk * 16 + quad * 4]);
            const unsigned* wb = Wpk + (size_t)(ch * 16 + kk * 4 + quad) * 768
                                     + (w * 48 + nl) * 4;
#pragma unroll
            for (int t = 0; t < 3; ++t) {
                const bf16x8 b = __builtin_bit_cast(bf16x8, *(const uint4*)(wb + t * 64));
                acc[0][t] = __builtin_amdgcn_mfma_f32_16x16x32_bf16(a0, b, acc[0][t], 0, 0, 0);
                acc[1][t] = __builtin_amdgcn_mfma_f32_16x16x32_bf16(a1, b, acc[1][t], 0, 0, 0);
            }
        }
        // no trailing barrier: next iteration writes the other LDS buffer
    }
    __syncthreads();

    const float QSCALE = 0.04508422f;    // D^-0.5 * log2(e): exp2-domain prescale
#pragma unroll
    for (int t = 0; t < 3; ++t) {
        const int n0c = w * 48 + t * 16;
        const int sel = n0c >> 6;
        const int col = (n0c & 63) + nl;
#pragma unroll
        for (int m = 0; m < 2; ++m) {
            if (sel == 0) {
#pragma unroll
                for (int reg = 0; reg < 4; ++reg)
                    Qbf[(row0 + m * 16 + quad * 4 + reg) * D_HEAD + col] =
                        bf16r(acc[m][t][reg] * QSCALE);
            } else if (sel == 1) {
#pragma unroll
                for (int reg = 0; reg < 4; ++reg)
                    Kbf[(row0 + m * 16 + quad * 4 + reg) * D_HEAD + col] =
                        bf16r(acc[m][t][reg]);
            } else {
                uint2 p2;
                p2.x = pk_bf16(acc[m][t][0], acc[m][t][1]);
                p2.y = pk_bf16(acc[m][t][2], acc[m][t][3]);
                *(uint2*)&Vbuf[col * 32 + m * 16 + quad * 4] = p2;
            }
        }
    }
    __syncthreads();
    {
        const int dim  = tid >> 2;
        const int tseg = (tid & 3) * 8;
        const long bb   = row0 >> 12;
        const int tpos0 = (int)(row0 & 4095);
        const uint4 v = *(const uint4*)&Vbuf[dim * 32 + tseg];
        *(uint4*)&Vt[((bb * 64 + dim) << 12) + tpos0 + tseg] = v;
    }
}

// ---------------- MFMA flash attention: R17 -------------------------------------------------
// R17 = R16 with nontemporal builtins on clang ext-vector types (compile fix).
// vs R14(=best): (a) SPLIT back to 8 (R5 proved SPLIT=16 hurts: doubled Po16 stream
// evicts K/V from L2 + doubled per-wave fixed overhead); (b) K-prefetch pipeline — next
// tile's K issues right after QK(m1) consumes the current K (same registers, anti-dep keeps
// order; sched_barrier(0) stops renamed hoisting), so K latency hides under softmax(m1)+PV;
// softmax(m0) sits between QK groups to cap live S regs at 16; (c) Po16/Pl stores are
// nontemporal so the once-written partials don't thrash the L2 holding K/V.
// Peak VGPR ~150 < (256,3) cap ~170; grid 512 = 2 blocks/CU so no residency loss.
__global__ __launch_bounds__(256, 3) void attn_kernel(
    const u16* __restrict__ Qbf, const u16* __restrict__ Kbf,
    const u16* __restrict__ Vt, u16* __restrict__ Po16, float* __restrict__ Pl)
{
    __shared__ __align__(16) u16 Pbuf[4][2][16 * 64];   // 16 KB

    const int tid   = threadIdx.x;
    const int w     = tid >> 6;
    const int lane  = tid & 63;
    const int nl    = lane & 15;
    const int quad  = lane >> 4;
    const int gid   = blockIdx.x;                // 0..511
    const int b     = gid & 3;                   // one batch per XCD pair (gid%8 RR)
    const int idx   = gid >> 2;                  // 0..127
    const int half  = idx & 1;
    const int pair  = idx >> 1;                  // 0..63
    const int sp    = half * 4 + w;              // global split 0..7

    const u16* Kb = Kbf + (size_t)b * T_SEQ * D_HEAD;
    const u16* Vb = Vt  + (size_t)b * D_HEAD * T_SEQ;

    const int tileA = 127 - pair;
    const int tileB = pair;
    const int nA = (tileA * 32 + 95) >> 6;       // 33..64
    const int nB = (tileB * 32 + 95) >> 6;       // nA + nB == 65 for all pairs
    const int cntA = (nA - sp + 7) >> 3;         // sp < 8 <= nA always
    const int ktB0 = sp + SPLIT * cntA - nA;     // in [0,8)
    const int cntB = (ktB0 < nB) ? ((nB - ktB0 + 7) >> 3) : 0;

#define LOADK(kt_) do {                                                              \
    const int _kk0 = (kt_) << 6;                                                     \
    _Pragma("unroll") for (int t = 0; t < 4; ++t) {                                  \
        const u16* kp = Kb + (size_t)(_kk0 + t * 16 + nl) * D_HEAD + quad * 8;       \
        kbuf[t][0] = *(const uint4*)kp;                                              \
        kbuf[t][1] = *(const uint4*)(kp + 32);                                       \
    }                                                                                \
} while (0)

#define LOADV(kt_) do {                                                              \
    const int _kv0 = (kt_) << 6;                                                     \
    _Pragma("unroll") for (int t = 0; t < 4; ++t) {                                  \
        const u16* vp = Vb + (size_t)(t * 16 + nl) * T_SEQ + _kv0 + quad * 8;        \
        vbuf[t][0] = *(const uint4*)vp;                                              \
        vbuf[t][1] = *(const uint4*)(vp + 32);                                       \
    }                                                                                \
} while (0)

#define QK_M(m_, Sd_) do {                                                           \
    _Pragma("unroll") for (int t = 0; t < 4; ++t) {                                  \
        f32x4 z = {};                                                                \
        z = __builtin_amdgcn_mfma_f32_16x16x32_bf16(qf[m_][0],                       \
                __builtin_bit_cast(bf16x8, kbuf[t][0]), z, 0, 0, 0);                 \
        Sd_[t] = __builtin_amdgcn_mfma_f32_16x16x32_bf16(qf[m_][1],                  \
                __builtin_bit_cast(bf16x8, kbuf[t][1]), z, 0, 0, 0);                 \
    }                                                                                \
} while (0)

#define SMAX_M(m_, Sd_) do {                                                         \
    const int _qb = wq0 + (m_) * 16;                                                 \
    if (k0c + 63 > _qb) {                                                            \
        _Pragma("unroll") for (int t = 0; t < 4; ++t)                                \
        _Pragma("unroll") for (int reg = 0; reg < 4; ++reg)                          \
            if (k0c + t * 16 + nl > _qb + quad * 4 + reg)                            \
                Sd_[t][reg] = -INFINITY;                                             \
    }                                                                                \
    _Pragma("unroll") for (int t = 0; t < 4; ++t)                                    \
    _Pragma("unroll") for (int reg = 0; reg < 4; ++reg)                              \
        Sd_[t][reg] = exp2f(Sd_[t][reg]);                                            \
    _Pragma("unroll") for (int reg = 0; reg < 4; ++reg)                              \
        l[m_][reg] += (Sd_[0][reg] + Sd_[1][reg]) + (Sd_[2][reg] + Sd_[3][reg]);     \
    u16* pb = Pbuf[w][m_];                                                           \
    _Pragma("unroll") for (int t = 0; t < 4; ++t) {                                  \
        const int g = 2 * t + (nl >> 3);                                             \
        _Pragma("unroll") for (int reg = 0; reg < 4; ++reg) {                        \
            const int q = quad * 4 + reg;                                            \
            pb[q * 64 + ((g ^ (q & 7)) * 8) + (nl & 7)] = bf16r(Sd_[t][reg]);        \
        }                                                                            \
    }                                                                                \
} while (0)

#define PV_M(m_) do {                                                                \
    const u16* pb = Pbuf[w][m_];                                                     \
    const bf16x8 pf0 = __builtin_bit_cast(bf16x8,                                    \
        *(const uint4*)&pb[nl * 64 + ((quad ^ (nl & 7)) * 8)]);                      \
    const bf16x8 pf1 = __builtin_bit_cast(bf16x8,                                    \
        *(const uint4*)&pb[nl * 64 + (((4 + quad) ^ (nl & 7)) * 8)]);                \
    _Pragma("unroll") for (int t = 0; t < 4; ++t) {                                  \
        Ot[m_][t] = __builtin_amdgcn_mfma_f32_16x16x32_bf16(pf0,                     \
                    __builtin_bit_cast(bf16x8, vbuf[t][0]), Ot[m_][t], 0, 0, 0);     \
        Ot[m_][t] = __builtin_amdgcn_mfma_f32_16x16x32_bf16(pf1,                     \
                    __builtin_bit_cast(bf16x8, vbuf[t][1]), Ot[m_][t], 0, 0, 0);     \
    }                                                                                \
} while (0)

    auto runTile = [&](const int tile, const int kt0, const int cnt) {
        const int wq0 = tile * 32;

        bf16x8 qf[2][2];
#pragma unroll
        for (int m = 0; m < 2; ++m) {
            const u16* qp = Qbf + ((size_t)b * T_SEQ + wq0 + m * 16 + nl) * D_HEAD + quad * 8;
            qf[m][0] = __builtin_bit_cast(bf16x8, *(const uint4*)qp);
            qf[m][1] = __builtin_bit_cast(bf16x8, *(const uint4*)(qp + 32));
        }

        f32x4 Ot[2][4] = {};
        float l[2][4] = {{0.f,0.f,0.f,0.f},{0.f,0.f,0.f,0.f}};

        uint4 kbuf[4][2], vbuf[4][2];
        if (cnt > 0) LOADK(kt0);
        int kt = kt0;
        for (int i = 0; i < cnt; ++i, kt += SPLIT) {
            const int k0c = kt << 6;
            f32x4 S0[4], S1[4];
            QK_M(0, S0);
            SMAX_M(0, S0);                   // between QK groups: caps live S regs at 16
            QK_M(1, S1);                     // last read of kbuf (this generation)
            LOADV(kt);
            __builtin_amdgcn_sched_barrier(0);   // prefetch must not hoist above QK
            if (i + 1 < cnt) LOADK(kt + SPLIT);  // K(i+1) hides under softmax(m1)+PV
            SMAX_M(1, S1);
            PV_M(0);
            PV_M(1);
        }

#pragma unroll
        for (int m = 0; m < 2; ++m) {
#pragma unroll
            for (int reg = 0; reg < 4; ++reg) {
                float s = l[m][reg];
                s += __shfl_xor(s, 1);
                s += __shfl_xor(s, 2);
                s += __shfl_xor(s, 4);
                s += __shfl_xor(s, 8);
                l[m][reg] = s;
            }
            const int strip = tile * 2 + m;
            const int bs = b * 256 + strip;
            u16* po = Po16 + ((size_t)sp * 1024 + bs) * 1024;
#pragma unroll
            for (int t = 0; t < 4; ++t) {
                u32x2 p2;
                p2[0] = pk_bf16(Ot[m][t][0], Ot[m][t][1]);
                p2[1] = pk_bf16(Ot[m][t][2], Ot[m][t][3]);
                __builtin_nontemporal_store(p2, (u32x2*)&po[(t * 16 + nl) * 16 + quad * 4]);
            }
            if (nl == 0) {
                const size_t gr = (size_t)b * T_SEQ + wq0 + m * 16;
#pragma unroll
                for (int reg = 0; reg < 4; ++reg)
                    __builtin_nontemporal_store(l[m][reg],
                        &Pl[(size_t)sp * NROWS + gr + quad * 4 + reg]);
            }
        }
    };

    runTile(tileA, sp,   cntA);
    runTile(tileB, ktB0, cntB);

#undef LOADK
#undef LOADV
#undef QK_M
#undef SMAX_M
#undef PV_M
}

// ---------------- merge K-split partials: O[row][col] = sum_sp Po / sum_sp Pl ---------------
// R17: 4-wave blocks (wave w sums sp in {w, w+4}), LDS combine -> 4x load parallelism;
// nontemporal loads (partials are read-once).
__global__ __launch_bounds__(256) void reduce_kernel(
    const u16* __restrict__ Po16, const float* __restrict__ Pl,
    float* __restrict__ O)
{
    __shared__ float part[4][16][64];    // 16 KB
    __shared__ float lsum[4][16];
    __shared__ float linv[16];
    const int tid = threadIdx.x;
    const int w   = tid >> 6;            // wave = sp-group
    const int c   = tid & 63;            // head dim
    const int bs  = blockIdx.x;
    const int b   = bs >> 8, strip = bs & 255;
    const size_t gr = (size_t)b * T_SEQ + strip * 16;

    float v[16] = {};
    float ls = 0.f;
#pragma unroll
    for (int i = 0; i < 2; ++i) {
        const int sp = w + i * 4;
        const u16* p = Po16 + ((size_t)sp * 1024 + bs) * 1024 + c * 16;
        const u32x4 x0 = __builtin_nontemporal_load((const u32x4*)p);
        const u32x4 x1 = __builtin_nontemporal_load((const u32x4*)p + 1);
        const unsigned uu[8] = {x0[0], x0[1], x0[2], x0[3], x1[0], x1[1], x1[2], x1[3]};
#pragma unroll
        for (int j = 0; j < 8; ++j) {
            v[2*j]   += __builtin_bit_cast(float, uu[j] << 16);
            v[2*j+1] += __builtin_bit_cast(float, uu[j] & 0xFFFF0000u);
        }
        if (c < 16) ls += Pl[(size_t)sp * NROWS + gr + c];
    }
#pragma unroll
    for (int r = 0; r < 16; ++r) part[w][r][c] = v[r];
    if (c < 16) lsum[w][c] = ls;
    __syncthreads();
    if (tid < 16)
        linv[tid] = 1.0f / (lsum[0][tid] + lsum[1][tid] + lsum[2][tid] + lsum[3][tid]);
    __syncthreads();
#pragma unroll
    for (int j = 0; j < 4; ++j) {
        const int r = w + j * 4;
        const float s = (part[0][r][c] + part[1][r][c]) + (part[2][r][c] + part[3][r][c]);
        O[(gr + r) * D_HEAD + c] = s * linv[r];
    }
}

extern "C" void kernel_launch(void* const* d_in, const int* in_sizes, int n_in,
                              void* d_out, int out_size, void* d_ws, size_t ws_size,
                              hipStream_t stream) {
    const float* x  = (const float*)d_in[0];
    const float* Wq = (const float*)d_in[1];
    const float* Wk = (const float*)d_in[2];
    const float* Wv = (const float*)d_in[3];
    float* out = (float*)d_out;

    const size_t rows = NROWS;                        // 16384
    u16* Qbf = (u16*)d_ws;                            // 2 MB
    u16* Kbf = Qbf + rows * D_HEAD;                   // 2 MB
    u16* Vt  = Kbf + rows * D_HEAD;                   // 2 MB (per-batch transposed [b][h][t])
    unsigned* Wpk = (unsigned*)(Vt + rows * D_HEAD);  // 384 KB
    u16* Po16 = (u16*)(Wpk + 128 * 192 * 4);          // SPLIT*16384*64 bf16 = 16 MB
    float* Pl = (float*)(Po16 + (size_t)SPLIT * rows * D_HEAD);  // 512 KB

    hipLaunchKernelGGL(packw_kernel, dim3(96), dim3(256), 0, stream,
                       Wq, Wk, Wv, Wpk);
    hipLaunchKernelGGL(qkv_kernel, dim3(rows / 32), dim3(256), 0, stream,
                       x, Wpk, Qbf, Kbf, Vt);
    hipLaunchKernelGGL(attn_kernel, dim3(512), dim3(256), 0, stream,
                       Qbf, Kbf, Vt, Po16, Pl);
    hipLaunchKernelGGL(reduce_kernel, dim3(NB * 256), dim3(64 * 4), 0, stream,
                       Po16, Pl, out);
}

// Round 8
// 159.656 us; speedup vs baseline: 1.2558x; 1.2558x over previous
//
#include <hip/hip_runtime.h>
#include <hip/hip_bf16.h>

#define D_MODEL 1024
#define D_HEAD  64
#define T_SEQ   4096
#define NB      4
#define NROWS   (NB * T_SEQ)      // 16384
#define SPLIT   8

typedef float f32x4 __attribute__((ext_vector_type(4)));
typedef __bf16 bf16x8 __attribute__((ext_vector_type(8)));
typedef unsigned short u16;
typedef unsigned u32x2 __attribute__((ext_vector_type(2)));
typedef unsigned u32x4 __attribute__((ext_vector_type(4)));

__device__ inline unsigned pk_bf16(float a, float b) {
    unsigned ua = __builtin_bit_cast(unsigned, a);
    unsigned ub = __builtin_bit_cast(unsigned, b);
    ua = (ua + 0x7FFFu + ((ua >> 16) & 1u)) >> 16;   // RNE
    ub = (ub + 0x7FFFu + ((ub >> 16) & 1u)) >> 16;
    return ua | (ub << 16);
}
__device__ inline u16 bf16r(float a) {
    unsigned ua = __builtin_bit_cast(unsigned, a);
    return (u16)((ua + 0x7FFFu + ((ua >> 16) & 1u)) >> 16);
}

// ---------------- W pre-pack: Wpk[kb][n][j] = W_sel[(kb*8+j)*64 + col], bf16 ----------------
__global__ __launch_bounds__(256) void packw_kernel(
    const float* __restrict__ Wq, const float* __restrict__ Wk,
    const float* __restrict__ Wv, unsigned* __restrict__ Wpk)
{
    const int id = blockIdx.x * 256 + threadIdx.x;   // 0..24575
    const int kb = id / 192;
    const int n  = id - kb * 192;
    const int sel = n >> 6, col = n & 63;
    const float* W = sel == 0 ? Wq : (sel == 1 ? Wk : Wv);
    float f[8];
#pragma unroll
    for (int j = 0; j < 8; ++j) f[j] = W[(kb * 8 + j) * 64 + col];
    uint4 o;
    o.x = pk_bf16(f[0], f[1]); o.y = pk_bf16(f[2], f[3]);
    o.z = pk_bf16(f[4], f[5]); o.w = pk_bf16(f[6], f[7]);
    *(uint4*)(Wpk + (size_t)id * 4) = o;
}

// ---------------- QKV projection: R18 — 16 rows/block, 1024 blocks --------------------------
// R8 theory: qkv was latency-starved at 2 blocks/CU (8 waves/CU); halving the row-tile
// doubles resident waves (4 blocks/CU, 16 waves/CU) so the per-chunk stage->sync->compute
// latency exposure interleaves across twice as many waves. Per-wave: one 16-row A fragment,
// acc[3] (Q|K|V 48 cols), 12 MFMA/chunk.
__global__ __launch_bounds__(256) void qkv_kernel(
    const float* __restrict__ x, const unsigned* __restrict__ Wpk,
    u16* __restrict__ Qbf, u16* __restrict__ Kbf, u16* __restrict__ Vt)
{
    __shared__ __align__(16) unsigned Xs[2][16 * 68];   // 16 rows x 128 bf16 (stride 136)
    __shared__ __align__(16) u16 Vbuf[64 * 16];         // V^T bounce: [dim 64][tpos 16]

    const int tid  = threadIdx.x;
    const int w    = tid >> 6;
    const int lane = tid & 63;
    const int nl   = lane & 15;
    const int quad = lane >> 4;
    const long row0 = (long)blockIdx.x * 16;

    const int srow = tid >> 5;          // staging: base row 0..7 (+8 second pass)
    const int scol = (tid & 31) * 4;    // staging col 0..124

    f32x4 acc[3] = {};

    f32x4 nx[2];
#pragma unroll
    for (int p = 0; p < 2; ++p)
        nx[p] = *(const f32x4*)(x + (row0 + p * 8 + srow) * D_MODEL + scol);

    for (int ch = 0; ch < 8; ++ch) {
        const int buf = ch & 1;
#pragma unroll
        for (int p = 0; p < 2; ++p) {
            uint2 pk2;
            pk2.x = pk_bf16(nx[p][0], nx[p][1]);
            pk2.y = pk_bf16(nx[p][2], nx[p][3]);
            *(uint2*)&Xs[buf][(p * 8 + srow) * 68 + (scol >> 1)] = pk2;
        }
        __syncthreads();
        if (ch < 7) {
#pragma unroll
            for (int p = 0; p < 2; ++p)
                nx[p] = *(const f32x4*)(x + (row0 + p * 8 + srow) * D_MODEL
                                          + (ch + 1) * 128 + scol);
        }
#pragma unroll
        for (int kk = 0; kk < 4; ++kk) {
            const bf16x8 a0 = __builtin_bit_cast(bf16x8,
                *(const uint4*)&Xs[buf][nl * 68 + kk * 16 + quad * 4]);
            const unsigned* wb = Wpk + (size_t)(ch * 16 + kk * 4 + quad) * 768
                                     + (w * 48 + nl) * 4;
#pragma unroll
            for (int t = 0; t < 3; ++t) {
                const bf16x8 b = __builtin_bit_cast(bf16x8, *(const uint4*)(wb + t * 64));
                acc[t] = __builtin_amdgcn_mfma_f32_16x16x32_bf16(a0, b, acc[t], 0, 0, 0);
            }
        }
        // no trailing barrier: next iteration stages the other LDS buffer
    }
    __syncthreads();

    const float QSCALE = 0.04508422f;    // D^-0.5 * log2(e): exp2-domain prescale
#pragma unroll
    for (int t = 0; t < 3; ++t) {
        const int n0c = w * 48 + t * 16;
        const int sel = n0c >> 6;
        const int col = (n0c & 63) + nl;
        if (sel == 0) {
#pragma unroll
            for (int reg = 0; reg < 4; ++reg)
                Qbf[(row0 + quad * 4 + reg) * D_HEAD + col] =
                    bf16r(acc[t][reg] * QSCALE);
        } else if (sel == 1) {
#pragma unroll
            for (int reg = 0; reg < 4; ++reg)
                Kbf[(row0 + quad * 4 + reg) * D_HEAD + col] =
                    bf16r(acc[t][reg]);
        } else {
            uint2 p2;
            p2.x = pk_bf16(acc[t][0], acc[t][1]);
            p2.y = pk_bf16(acc[t][2], acc[t][3]);
            *(uint2*)&Vbuf[col * 16 + quad * 4] = p2;
        }
    }
    __syncthreads();
    {
        const int dim  = tid >> 2;           // 0..63
        const int tseg = (tid & 3) * 4;      // 0,4,8,12
        const long bb   = row0 >> 12;
        const int tpos0 = (int)(row0 & 4095);
        const uint2 v = *(const uint2*)&Vbuf[dim * 16 + tseg];
        *(uint2*)&Vt[((bb * 64 + dim) << 12) + tpos0 + tseg] = v;
    }
}

// ---------------- MFMA flash attention: R18 = EXACT R14 body (proven 45.5 us) ---------------
// Phase-split per K-tile (only ONE 32-reg load buffer live at a time; R2/R4/R7 proved any
// cross-iteration prefetch triggers scratch spills at this body's pressure). Only delta vs
// R14: Po16/Pl epilogue stores are nontemporal (partials are write-once/read-once; keep the
// 16 MB stream from evicting K/V in L2). Balanced pairing (127-p, p) = 65 K-tiles/pair;
// 512 blocks; one batch per XCD via gid&3 (gid%8 RR).
__global__ __launch_bounds__(256, 3) void attn_kernel(
    const u16* __restrict__ Qbf, const u16* __restrict__ Kbf,
    const u16* __restrict__ Vt, u16* __restrict__ Po16, float* __restrict__ Pl)
{
    __shared__ __align__(16) u16 Pbuf[4][2][16 * 64];   // 16 KB

    const int tid   = threadIdx.x;
    const int w     = tid >> 6;
    const int lane  = tid & 63;
    const int nl    = lane & 15;
    const int quad  = lane >> 4;
    const int gid   = blockIdx.x;                // 0..511
    const int b     = gid & 3;                   // one batch per XCD pair (gid%8 RR)
    const int idx   = gid >> 2;                  // 0..127
    const int half  = idx & 1;
    const int pair  = idx >> 1;                  // 0..63
    const int sp    = half * 4 + w;              // global split 0..7

    const u16* Kb = Kbf + (size_t)b * T_SEQ * D_HEAD;
    const u16* Vb = Vt  + (size_t)b * D_HEAD * T_SEQ;

    const int tileA = 127 - pair;
    const int tileB = pair;
    const int nA = (tileA * 32 + 95) >> 6;       // 33..64
    const int nB = (tileB * 32 + 95) >> 6;       // nA + nB == 65 for all pairs
    const int cntA = (nA - sp + 7) >> 3;         // sp < 8 <= nA always
    const int ktB0 = sp + SPLIT * cntA - nA;     // in [0,8)
    const int cntB = (ktB0 < nB) ? ((nB - ktB0 + 7) >> 3) : 0;

// one K-tile: phase-split so only one 32-reg load buffer is live at any point
#define COMPUTEKV(kt_) do {                                                          \
    const int _k0 = (kt_) << 6;                                                      \
    uint4 buf[4][2];                                                                 \
    _Pragma("unroll") for (int t = 0; t < 4; ++t) {                                  \
        const u16* kp = Kb + (size_t)(_k0 + t * 16 + nl) * D_HEAD + quad * 8;        \
        buf[t][0] = *(const uint4*)kp;                                               \
        buf[t][1] = *(const uint4*)(kp + 32);                                        \
    }                                                                                \
    f32x4 S[2][4];                                                                   \
    _Pragma("unroll") for (int m = 0; m < 2; ++m)                                    \
    _Pragma("unroll") for (int t = 0; t < 4; ++t) {                                  \
        f32x4 z = {};                                                                \
        z = __builtin_amdgcn_mfma_f32_16x16x32_bf16(qf[m][0],                        \
                __builtin_bit_cast(bf16x8, buf[t][0]), z, 0, 0, 0);                  \
        S[m][t] = __builtin_amdgcn_mfma_f32_16x16x32_bf16(qf[m][1],                  \
                __builtin_bit_cast(bf16x8, buf[t][1]), z, 0, 0, 0);                  \
    }                                                                                \
    uint4 vbuf[4][2];   /* K buffer dead -> allocator reuses its slots */            \
    _Pragma("unroll") for (int t = 0; t < 4; ++t) {                                  \
        const u16* vp = Vb + (size_t)(t * 16 + nl) * T_SEQ + _k0 + quad * 8;         \
        vbuf[t][0] = *(const uint4*)vp;                                              \
        vbuf[t][1] = *(const uint4*)(vp + 32);                                       \
    }                                                                                \
    _Pragma("unroll") for (int m = 0; m < 2; ++m) {                                  \
        const int _qb = wq0 + m * 16;                                                \
        if (_k0 + 63 > _qb) {                                                        \
            _Pragma("unroll") for (int t = 0; t < 4; ++t)                            \
            _Pragma("unroll") for (int reg = 0; reg < 4; ++reg)                      \
                if (_k0 + t * 16 + nl > _qb + quad * 4 + reg)                        \
                    S[m][t][reg] = -INFINITY;                                        \
        }                                                                            \
        _Pragma("unroll") for (int t = 0; t < 4; ++t)                                \
        _Pragma("unroll") for (int reg = 0; reg < 4; ++reg)                          \
            S[m][t][reg] = exp2f(S[m][t][reg]);                                      \
        _Pragma("unroll") for (int reg = 0; reg < 4; ++reg)                          \
            l[m][reg] += (S[m][0][reg] + S[m][1][reg])                               \
                       + (S[m][2][reg] + S[m][3][reg]);                              \
        u16* pb = Pbuf[w][m];                                                        \
        _Pragma("unroll") for (int t = 0; t < 4; ++t) {                              \
            const int g = 2 * t + (nl >> 3);                                         \
            _Pragma("unroll") for (int reg = 0; reg < 4; ++reg) {                    \
                const int q = quad * 4 + reg;                                        \
                pb[q * 64 + ((g ^ (q & 7)) * 8) + (nl & 7)] = bf16r(S[m][t][reg]);   \
            }                                                                        \
        }                                                                            \
    }                                                                                \
    _Pragma("unroll") for (int m = 0; m < 2; ++m) {                                  \
        const u16* pb = Pbuf[w][m];                                                  \
        const bf16x8 pf0 = __builtin_bit_cast(bf16x8,                                \
            *(const uint4*)&pb[nl * 64 + ((quad ^ (nl & 7)) * 8)]);                  \
        const bf16x8 pf1 = __builtin_bit_cast(bf16x8,                                \
            *(const uint4*)&pb[nl * 64 + (((4 + quad) ^ (nl & 7)) * 8)]);            \
        _Pragma("unroll") for (int t = 0; t < 4; ++t) {                              \
            Ot[m][t] = __builtin_amdgcn_mfma_f32_16x16x32_bf16(pf0,                  \
                        __builtin_bit_cast(bf16x8, vbuf[t][0]), Ot[m][t], 0, 0, 0);  \
            Ot[m][t] = __builtin_amdgcn_mfma_f32_16x16x32_bf16(pf1,                  \
                        __builtin_bit_cast(bf16x8, vbuf[t][1]), Ot[m][t], 0, 0, 0);  \
        }                                                                            \
    }                                                                                \
} while (0)

    auto runTile = [&](const int tile, const int kt0, const int cnt) {
        const int wq0 = tile * 32;

        bf16x8 qf[2][2];
#pragma unroll
        for (int m = 0; m < 2; ++m) {
            const u16* qp = Qbf + ((size_t)b * T_SEQ + wq0 + m * 16 + nl) * D_HEAD + quad * 8;
            qf[m][0] = __builtin_bit_cast(bf16x8, *(const uint4*)qp);
            qf[m][1] = __builtin_bit_cast(bf16x8, *(const uint4*)(qp + 32));
        }

        f32x4 Ot[2][4] = {};
        float l[2][4] = {{0.f,0.f,0.f,0.f},{0.f,0.f,0.f,0.f}};

        int kt = kt0;
        for (int i = 0; i < cnt; ++i, kt += SPLIT)
            COMPUTEKV(kt);

#pragma unroll
        for (int m = 0; m < 2; ++m) {
#pragma unroll
            for (int reg = 0; reg < 4; ++reg) {
                float s = l[m][reg];
                s += __shfl_xor(s, 1);
                s += __shfl_xor(s, 2);
                s += __shfl_xor(s, 4);
                s += __shfl_xor(s, 8);
                l[m][reg] = s;
            }
            const int strip = tile * 2 + m;
            const int bs = b * 256 + strip;
            u16* po = Po16 + ((size_t)sp * 1024 + bs) * 1024;
#pragma unroll
            for (int t = 0; t < 4; ++t) {
                u32x2 p2;
                p2[0] = pk_bf16(Ot[m][t][0], Ot[m][t][1]);
                p2[1] = pk_bf16(Ot[m][t][2], Ot[m][t][3]);
                __builtin_nontemporal_store(p2, (u32x2*)&po[(t * 16 + nl) * 16 + quad * 4]);
            }
            if (nl == 0) {
                const size_t gr = (size_t)b * T_SEQ + wq0 + m * 16;
#pragma unroll
                for (int reg = 0; reg < 4; ++reg)
                    __builtin_nontemporal_store(l[m][reg],
                        &Pl[(size_t)sp * NROWS + gr + quad * 4 + reg]);
            }
        }
    };

    runTile(tileA, sp,   cntA);
    runTile(tileB, ktB0, cntB);

#undef COMPUTEKV
}

// ---------------- merge K-split partials: O[row][col] = sum_sp Po / sum_sp Pl ---------------
// 4-wave blocks (wave w sums sp in {w, w+4}), LDS combine -> 4x load parallelism;
// nontemporal loads (partials are read-once).
__global__ __launch_bounds__(256) void reduce_kernel(
    const u16* __restrict__ Po16, const float* __restrict__ Pl,
    float* __restrict__ O)
{
    __shared__ float part[4][16][64];    // 16 KB
    __shared__ float lsum[4][16];
    __shared__ float linv[16];
    const int tid = threadIdx.x;
    const int w   = tid >> 6;            // wave = sp-group
    const int c   = tid & 63;            // head dim
    const int bs  = blockIdx.x;
    const int b   = bs >> 8, strip = bs & 255;
    const size_t gr = (size_t)b * T_SEQ + strip * 16;

    float v[16] = {};
    float ls = 0.f;
#pragma unroll
    for (int i = 0; i < 2; ++i) {
        const int sp = w + i * 4;
        const u16* p = Po16 + ((size_t)sp * 1024 + bs) * 1024 + c * 16;
        const u32x4 x0 = __builtin_nontemporal_load((const u32x4*)p);
        const u32x4 x1 = __builtin_nontemporal_load((const u32x4*)p + 1);
        const unsigned uu[8] = {x0[0], x0[1], x0[2], x0[3], x1[0], x1[1], x1[2], x1[3]};
#pragma unroll
        for (int j = 0; j < 8; ++j) {
            v[2*j]   += __builtin_bit_cast(float, uu[j] << 16);
            v[2*j+1] += __builtin_bit_cast(float, uu[j] & 0xFFFF0000u);
        }
        if (c < 16) ls += Pl[(size_t)sp * NROWS + gr + c];
    }
#pragma unroll
    for (int r = 0; r < 16; ++r) part[w][r][c] = v[r];
    if (c < 16) lsum[w][c] = ls;
    __syncthreads();
    if (tid < 16)
        linv[tid] = 1.0f / (lsum[0][tid] + lsum[1][tid] + lsum[2][tid] + lsum[3][tid]);
    __syncthreads();
#pragma unroll
    for (int j = 0; j < 4; ++j) {
        const int r = w + j * 4;
        const float s = (part[0][r][c] + part[1][r][c]) + (part[2][r][c] + part[3][r][c]);
        O[(gr + r) * D_HEAD + c] = s * linv[r];
    }
}

extern "C" void kernel_launch(void* const* d_in, const int* in_sizes, int n_in,
                              void* d_out, int out_size, void* d_ws, size_t ws_size,
                              hipStream_t stream) {
    const float* x  = (const float*)d_in[0];
    const float* Wq = (const float*)d_in[1];
    const float* Wk = (const float*)d_in[2];
    const float* Wv = (const float*)d_in[3];
    float* out = (float*)d_out;

    const size_t rows = NROWS;                        // 16384
    u16* Qbf = (u16*)d_ws;                            // 2 MB
    u16* Kbf = Qbf + rows * D_HEAD;                   // 2 MB
    u16* Vt  = Kbf + rows * D_HEAD;                   // 2 MB (per-batch transposed [b][h][t])
    unsigned* Wpk = (unsigned*)(Vt + rows * D_HEAD);  // 384 KB
    u16* Po16 = (u16*)(Wpk + 128 * 192 * 4);          // SPLIT*16384*64 bf16 = 16 MB
    float* Pl = (float*)(Po16 + (size_t)SPLIT * rows * D_HEAD);  // 512 KB

    hipLaunchKernelGGL(packw_kernel, dim3(96), dim3(256), 0, stream,
                       Wq, Wk, Wv, Wpk);
    hipLaunchKernelGGL(qkv_kernel, dim3(rows / 16), dim3(256), 0, stream,
                       x, Wpk, Qbf, Kbf, Vt);
    hipLaunchKernelGGL(attn_kernel, dim3(512), dim3(256), 0, stream,
                       Qbf, Kbf, Vt, Po16, Pl);
    hipLaunchKernelGGL(reduce_kernel, dim3(NB * 256), dim3(64 * 4), 0, stream,
                       Po16, Pl, out);
}

// Round 9
// 140.271 us; speedup vs baseline: 1.4294x; 1.1382x over previous
//
#include <hip/hip_runtime.h>
#include <hip/hip_bf16.h>

#define D_MODEL 1024
#define D_HEAD  64
#define T_SEQ   4096
#define NB      4
#define NROWS   (NB * T_SEQ)      // 16384
#define SPLIT   8

typedef float f32x4 __attribute__((ext_vector_type(4)));
typedef __bf16 bf16x8 __attribute__((ext_vector_type(8)));
typedef unsigned short u16;
typedef unsigned u32x2 __attribute__((ext_vector_type(2)));
typedef unsigned u32x4 __attribute__((ext_vector_type(4)));

__device__ inline unsigned pk_bf16(float a, float b) {
    unsigned ua = __builtin_bit_cast(unsigned, a);
    unsigned ub = __builtin_bit_cast(unsigned, b);
    ua = (ua + 0x7FFFu + ((ua >> 16) & 1u)) >> 16;   // RNE
    ub = (ub + 0x7FFFu + ((ub >> 16) & 1u)) >> 16;
    return ua | (ub << 16);
}
__device__ inline u16 bf16r(float a) {
    unsigned ua = __builtin_bit_cast(unsigned, a);
    return (u16)((ua + 0x7FFFu + ((ua >> 16) & 1u)) >> 16);
}

// async global->LDS, 16B per lane, no VGPR staging
__device__ inline void gload_lds16(const void* g, void* l) {
    __builtin_amdgcn_global_load_lds(
        (const __attribute__((address_space(1))) void*)g,
        (__attribute__((address_space(3))) void*)l, 16, 0, 0);
}

// ---------------- W pre-pack: Wpk[kb][n][j] = W_sel[(kb*8+j)*64 + col], bf16 ----------------
__global__ __launch_bounds__(256) void packw_kernel(
    const float* __restrict__ Wq, const float* __restrict__ Wk,
    const float* __restrict__ Wv, unsigned* __restrict__ Wpk)
{
    const int id = blockIdx.x * 256 + threadIdx.x;   // 0..24575
    const int kb = id / 192;
    const int n  = id - kb * 192;
    const int sel = n >> 6, col = n & 63;
    const float* W = sel == 0 ? Wq : (sel == 1 ? Wk : Wv);
    float f[8];
#pragma unroll
    for (int j = 0; j < 8; ++j) f[j] = W[(kb * 8 + j) * 64 + col];
    uint4 o;
    o.x = pk_bf16(f[0], f[1]); o.y = pk_bf16(f[2], f[3]);
    o.z = pk_bf16(f[4], f[5]); o.w = pk_bf16(f[6], f[7]);
    *(uint4*)(Wpk + (size_t)id * 4) = o;
}

// ---------------- QKV projection: 32 rows/block, 512 blocks (R3/R5 proven form) -------------
__global__ __launch_bounds__(256) void qkv_kernel(
    const float* __restrict__ x, const unsigned* __restrict__ Wpk,
    u16* __restrict__ Qbf, u16* __restrict__ Kbf, u16* __restrict__ Vt)
{
    __shared__ __align__(16) unsigned Xs[2][32 * 68];   // 32 rows x 128 bf16 (stride 136)
    __shared__ __align__(16) u16 Vbuf[64 * 32];         // V^T bounce: [dim 64][tpos 32]

    const int tid  = threadIdx.x;
    const int w    = tid >> 6;
    const int lane = tid & 63;
    const int nl   = lane & 15;
    const int quad = lane >> 4;
    const long row0 = (long)blockIdx.x * 32;

    const int srow = tid >> 5;          // staging: base row 0..7 (+8 per pass)
    const int scol = (tid & 31) * 4;    // staging col 0..124

    f32x4 acc[2][3] = {};

    float4 nx[4];
#pragma unroll
    for (int p = 0; p < 4; ++p)
        nx[p] = *(const float4*)(x + (row0 + p * 8 + srow) * D_MODEL + scol);

    for (int ch = 0; ch < 8; ++ch) {
        const int buf = ch & 1;
#pragma unroll
        for (int p = 0; p < 4; ++p) {
            uint2 pk2;
            pk2.x = pk_bf16(nx[p].x, nx[p].y);
            pk2.y = pk_bf16(nx[p].z, nx[p].w);
            *(uint2*)&Xs[buf][(p * 8 + srow) * 68 + (scol >> 1)] = pk2;
        }
        __syncthreads();
        if (ch < 7) {
#pragma unroll
            for (int p = 0; p < 4; ++p)
                nx[p] = *(const float4*)(x + (row0 + p * 8 + srow) * D_MODEL
                                           + (ch + 1) * 128 + scol);
        }
#pragma unroll
        for (int kk = 0; kk < 4; ++kk) {
            const bf16x8 a0 = __builtin_bit_cast(bf16x8,
                *(const uint4*)&Xs[buf][nl * 68 + kk * 16 + quad * 4]);
            const bf16x8 a1 = __builtin_bit_cast(bf16x8,
                *(const uint4*)&Xs[buf][(16 + nl) * 68 + kk * 16 + quad * 4]);
            const unsigned* wb = Wpk + (size_t)(ch * 16 + kk * 4 + quad) * 768
                                     + (w * 48 + nl) * 4;
#pragma unroll
            for (int t = 0; t < 3; ++t) {
                const bf16x8 b = __builtin_bit_cast(bf16x8, *(const uint4*)(wb + t * 64));
                acc[0][t] = __builtin_amdgcn_mfma_f32_16x16x32_bf16(a0, b, acc[0][t], 0, 0, 0);
                acc[1][t] = __builtin_amdgcn_mfma_f32_16x16x32_bf16(a1, b, acc[1][t], 0, 0, 0);
            }
        }
        // no trailing barrier: next iteration stages the other LDS buffer
    }
    __syncthreads();

    const float QSCALE = 0.04508422f;    // D^-0.5 * log2(e): exp2-domain prescale
#pragma unroll
    for (int t = 0; t < 3; ++t) {
        const int n0c = w * 48 + t * 16;
        const int sel = n0c >> 6;
        const int col = (n0c & 63) + nl;
#pragma unroll
        for (int m = 0; m < 2; ++m) {
            if (sel == 0) {
#pragma unroll
                for (int reg = 0; reg < 4; ++reg)
                    Qbf[(row0 + m * 16 + quad * 4 + reg) * D_HEAD + col] =
                        bf16r(acc[m][t][reg] * QSCALE);
            } else if (sel == 1) {
#pragma unroll
                for (int reg = 0; reg < 4; ++reg)
                    Kbf[(row0 + m * 16 + quad * 4 + reg) * D_HEAD + col] =
                        bf16r(acc[m][t][reg]);
            } else {
                uint2 p2;
                p2.x = pk_bf16(acc[m][t][0], acc[m][t][1]);
                p2.y = pk_bf16(acc[m][t][2], acc[m][t][3]);
                *(uint2*)&Vbuf[col * 32 + m * 16 + quad * 4] = p2;
            }
        }
    }
    __syncthreads();
    {
        const int dim  = tid >> 2;
        const int tseg = (tid & 3) * 8;
        const long bb   = row0 >> 12;
        const int tpos0 = (int)(row0 & 4095);
        const uint4 v = *(const uint4*)&Vbuf[dim * 32 + tseg];
        *(uint4*)&Vt[((bb * 64 + dim) << 12) + tpos0 + tseg] = v;
    }
}

// ---------------- MFMA flash attention: R19 — cooperative LDS-staged K/V --------------------
// Theory: R3 body stalls ~4800 cy/tile on serial per-wave K then V global-load chains, and
// register prefetch always spills (R2/R7). Fix: 4 waves share one (b, 128-row q-block, sp);
// K/V tiles staged into double-buffered LDS via global_load_lds (zero VGPR cost), next tile
// issued before computing current (one barrier/tile). Fragment reads are ds_read_b128 with
// XOR swizzle (store-side: pre-swizzled global source; read-side: granule ^= row&7) ->
// conflict-free. Per-wave compute body verbatim from R14. K/V L2 traffic /4.
// Pairing (31-p, p): 66 K-tiles/pair constant. 512 blocks = 2/CU, LDS 48KB, lb(256,2).
__global__ __launch_bounds__(256, 2) void attn_kernel(
    const u16* __restrict__ Qbf, const u16* __restrict__ Kbf,
    const u16* __restrict__ Vt, u16* __restrict__ Po16, float* __restrict__ Pl)
{
    __shared__ __align__(16) u16 Kls[2][4096];          // 2 x 64 keys x 64 dims (swizzled)
    __shared__ __align__(16) u16 Vls[2][4096];          // 2 x 64 dims x 64 keys (swizzled)
    __shared__ __align__(16) u16 Pbuf[4][2][16 * 64];   // 16 KB

    const int tid   = threadIdx.x;
    const int w     = tid >> 6;
    const int lane  = tid & 63;
    const int nl    = lane & 15;
    const int quad  = lane >> 4;
    const int gid   = blockIdx.x;                // 0..511
    const int b     = gid & 3;                   // one batch per XCD pair (gid%8 RR)
    const int idx   = gid >> 2;                  // 0..127
    const int sp    = idx & 7;                   // block-uniform K-split 0..7
    const int pair  = idx >> 3;                  // 0..15

    const u16* Kb = Kbf + (size_t)b * T_SEQ * D_HEAD;
    const u16* Vb = Vt  + (size_t)b * D_HEAD * T_SEQ;

    const int qbA = 31 - pair;                   // q-blocks of 128 rows; pair (31-p, p)
    const int qbB = pair;
    const int nA = 2 * qbA + 2;                  // K-tiles needed; nA + nB == 66
    const int nB = 2 * qbB + 2;
    const int cntA = (nA - sp + 7) >> 3;         // sp < 8 <= nA always
    const int ktB0 = sp + SPLIT * cntA - nA;     // in [0,8)
    const int cntB = (ktB0 < nB) ? ((nB - ktB0 + 7) >> 3) : 0;

    // per-lane invariants: stage-source swizzle + ds_read offsets (u16 units)
    const int swz   = ((lane & 7) ^ ((lane >> 3) & 7)) * 8;  // granule XOR, 8 elems each
    const int stgk  = ((lane >> 3) << 6) + swz;              // K: row (lane>>3), 64/row
    const int stgv  = ((lane >> 3) << 12) + swz;             // V: row (lane>>3), 4096/row
    const int offh0 = nl * 64 + ((quad ^ (nl & 7)) << 3);
    const int offh1 = nl * 64 + (((quad + 4) ^ (nl & 7)) << 3);

// stage one 64-key K tile + V tile into LDS buffer cur_ (wave w issues its 4 of 16 loads)
#define STAGE(cur_, kt_) do {                                                        \
    const int _s0 = (kt_) << 6;                                                      \
    _Pragma("unroll") for (int jj = 0; jj < 2; ++jj) {                               \
        const int j = w * 2 + jj;                                                    \
        gload_lds16(Kb + (size_t)(_s0 + 8 * j) * 64 + stgk, &Kls[cur_][j * 512]);    \
        gload_lds16(Vb + (size_t)(8 * j) * 4096 + _s0 + stgv, &Vls[cur_][j * 512]);  \
    }                                                                                \
} while (0)

// one K-tile from LDS: body verbatim R14 with global loads -> swizzled ds_read_b128
#define COMPUTEKV(cur_, kt_) do {                                                    \
    const int _k0 = (kt_) << 6;                                                      \
    uint4 buf[4][2];                                                                 \
    _Pragma("unroll") for (int t = 0; t < 4; ++t) {                                  \
        buf[t][0] = *(const uint4*)&Kls[cur_][t * 1024 + offh0];                     \
        buf[t][1] = *(const uint4*)&Kls[cur_][t * 1024 + offh1];                     \
    }                                                                                \
    f32x4 S[2][4];                                                                   \
    _Pragma("unroll") for (int m = 0; m < 2; ++m)                                    \
    _Pragma("unroll") for (int t = 0; t < 4; ++t) {                                  \
        f32x4 z = {};                                                                \
        z = __builtin_amdgcn_mfma_f32_16x16x32_bf16(qf[m][0],                        \
                __builtin_bit_cast(bf16x8, buf[t][0]), z, 0, 0, 0);                  \
        S[m][t] = __builtin_amdgcn_mfma_f32_16x16x32_bf16(qf[m][1],                  \
                __builtin_bit_cast(bf16x8, buf[t][1]), z, 0, 0, 0);                  \
    }                                                                                \
    uint4 vbuf[4][2];                                                                \
    _Pragma("unroll") for (int t = 0; t < 4; ++t) {                                  \
        vbuf[t][0] = *(const uint4*)&Vls[cur_][t * 1024 + offh0];                    \
        vbuf[t][1] = *(const uint4*)&Vls[cur_][t * 1024 + offh1];                    \
    }                                                                                \
    _Pragma("unroll") for (int m = 0; m < 2; ++m) {                                  \
        const int _qb = wq0 + m * 16;                                                \
        if (_k0 + 63 > _qb) {                                                        \
            _Pragma("unroll") for (int t = 0; t < 4; ++t)                            \
            _Pragma("unroll") for (int reg = 0; reg < 4; ++reg)                      \
                if (_k0 + t * 16 + nl > _qb + quad * 4 + reg)                        \
                    S[m][t][reg] = -INFINITY;                                        \
        }                                                                            \
        _Pragma("unroll") for (int t = 0; t < 4; ++t)                                \
        _Pragma("unroll") for (int reg = 0; reg < 4; ++reg)                          \
            S[m][t][reg] = exp2f(S[m][t][reg]);                                      \
        _Pragma("unroll") for (int reg = 0; reg < 4; ++reg)                          \
            l[m][reg] += (S[m][0][reg] + S[m][1][reg])                               \
                       + (S[m][2][reg] + S[m][3][reg]);                              \
        u16* pb = Pbuf[w][m];                                                        \
        _Pragma("unroll") for (int t = 0; t < 4; ++t) {                              \
            const int g = 2 * t + (nl >> 3);                                         \
            _Pragma("unroll") for (int reg = 0; reg < 4; ++reg) {                    \
                const int q = quad * 4 + reg;                                        \
                pb[q * 64 + ((g ^ (q & 7)) * 8) + (nl & 7)] = bf16r(S[m][t][reg]);   \
            }                                                                        \
        }                                                                            \
    }                                                                                \
    _Pragma("unroll") for (int m = 0; m < 2; ++m) {                                  \
        const u16* pb = Pbuf[w][m];                                                  \
        const bf16x8 pf0 = __builtin_bit_cast(bf16x8,                                \
            *(const uint4*)&pb[nl * 64 + ((quad ^ (nl & 7)) * 8)]);                  \
        const bf16x8 pf1 = __builtin_bit_cast(bf16x8,                                \
            *(const uint4*)&pb[nl * 64 + (((4 + quad) ^ (nl & 7)) * 8)]);            \
        _Pragma("unroll") for (int t = 0; t < 4; ++t) {                              \
            Ot[m][t] = __builtin_amdgcn_mfma_f32_16x16x32_bf16(pf0,                  \
                        __builtin_bit_cast(bf16x8, vbuf[t][0]), Ot[m][t], 0, 0, 0);  \
            Ot[m][t] = __builtin_amdgcn_mfma_f32_16x16x32_bf16(pf1,                  \
                        __builtin_bit_cast(bf16x8, vbuf[t][1]), Ot[m][t], 0, 0, 0);  \
        }                                                                            \
    }                                                                                \
} while (0)

    auto runTile = [&](const int qb, const int kt0, const int cnt) {
        const int wq0 = qb * 128 + w * 32;       // this wave's 32 q-rows

        bf16x8 qf[2][2];
#pragma unroll
        for (int m = 0; m < 2; ++m) {
            const u16* qp = Qbf + ((size_t)b * T_SEQ + wq0 + m * 16 + nl) * D_HEAD + quad * 8;
            qf[m][0] = __builtin_bit_cast(bf16x8, *(const uint4*)qp);
            qf[m][1] = __builtin_bit_cast(bf16x8, *(const uint4*)(qp + 32));
        }

        f32x4 Ot[2][4] = {};
        float l[2][4] = {{0.f,0.f,0.f,0.f},{0.f,0.f,0.f,0.f}};

        int kt = kt0;
        if (cnt > 0) STAGE(0, kt);
        __syncthreads();                          // drain stage (vmcnt 0) for all waves
        for (int i = 0; i < cnt; ++i, kt += SPLIT) {
            if (i + 1 < cnt) STAGE((i + 1) & 1, kt + SPLIT);   // async prefetch, no VGPRs
            COMPUTEKV(i & 1, kt);
            __syncthreads();                      // next buf staged + all readers done
        }

#pragma unroll
        for (int m = 0; m < 2; ++m) {
#pragma unroll
            for (int reg = 0; reg < 4; ++reg) {
                float s = l[m][reg];
                s += __shfl_xor(s, 1);
                s += __shfl_xor(s, 2);
                s += __shfl_xor(s, 4);
                s += __shfl_xor(s, 8);
                l[m][reg] = s;
            }
            const int strip = qb * 8 + w * 2 + m;
            const int bs = b * 256 + strip;
            u16* po = Po16 + ((size_t)sp * 1024 + bs) * 1024;
#pragma unroll
            for (int t = 0; t < 4; ++t) {
                u32x2 p2;
                p2[0] = pk_bf16(Ot[m][t][0], Ot[m][t][1]);
                p2[1] = pk_bf16(Ot[m][t][2], Ot[m][t][3]);
                __builtin_nontemporal_store(p2, (u32x2*)&po[(t * 16 + nl) * 16 + quad * 4]);
            }
            if (nl == 0) {
                const size_t gr = (size_t)b * T_SEQ + qb * 128 + w * 32 + m * 16;
#pragma unroll
                for (int reg = 0; reg < 4; ++reg)
                    __builtin_nontemporal_store(l[m][reg],
                        &Pl[(size_t)sp * NROWS + gr + quad * 4 + reg]);
            }
        }
    };

    runTile(qbA, sp,   cntA);
    runTile(qbB, ktB0, cntB);

#undef STAGE
#undef COMPUTEKV
}

// ---------------- merge K-split partials: O[row][col] = sum_sp Po / sum_sp Pl ---------------
__global__ __launch_bounds__(256) void reduce_kernel(
    const u16* __restrict__ Po16, const float* __restrict__ Pl,
    float* __restrict__ O)
{
    __shared__ float part[4][16][64];    // 16 KB
    __shared__ float lsum[4][16];
    __shared__ float linv[16];
    const int tid = threadIdx.x;
    const int w   = tid >> 6;            // wave = sp-group
    const int c   = tid & 63;            // head dim
    const int bs  = blockIdx.x;
    const int b   = bs >> 8, strip = bs & 255;
    const size_t gr = (size_t)b * T_SEQ + strip * 16;

    float v[16] = {};
    float ls = 0.f;
#pragma unroll
    for (int i = 0; i < 2; ++i) {
        const int sp = w + i * 4;
        const u16* p = Po16 + ((size_t)sp * 1024 + bs) * 1024 + c * 16;
        const u32x4 x0 = __builtin_nontemporal_load((const u32x4*)p);
        const u32x4 x1 = __builtin_nontemporal_load((const u32x4*)p + 1);
        const unsigned uu[8] = {x0[0], x0[1], x0[2], x0[3], x1[0], x1[1], x1[2], x1[3]};
#pragma unroll
        for (int j = 0; j < 8; ++j) {
            v[2*j]   += __builtin_bit_cast(float, uu[j] << 16);
            v[2*j+1] += __builtin_bit_cast(float, uu[j] & 0xFFFF0000u);
        }
        if (c < 16) ls += Pl[(size_t)sp * NROWS + gr + c];
    }
#pragma unroll
    for (int r = 0; r < 16; ++r) part[w][r][c] = v[r];
    if (c < 16) lsum[w][c] = ls;
    __syncthreads();
    if (tid < 16)
        linv[tid] = 1.0f / (lsum[0][tid] + lsum[1][tid] + lsum[2][tid] + lsum[3][tid]);
    __syncthreads();
#pragma unroll
    for (int j = 0; j < 4; ++j) {
        const int r = w + j * 4;
        const float s = (part[0][r][c] + part[1][r][c]) + (part[2][r][c] + part[3][r][c]);
        O[(gr + r) * D_HEAD + c] = s * linv[r];
    }
}

extern "C" void kernel_launch(void* const* d_in, const int* in_sizes, int n_in,
                              void* d_out, int out_size, void* d_ws, size_t ws_size,
                              hipStream_t stream) {
    const float* x  = (const float*)d_in[0];
    const float* Wq = (const float*)d_in[1];
    const float* Wk = (const float*)d_in[2];
    const float* Wv = (const float*)d_in[3];
    float* out = (float*)d_out;

    const size_t rows = NROWS;                        // 16384
    u16* Qbf = (u16*)d_ws;                            // 2 MB
    u16* Kbf = Qbf + rows * D_HEAD;                   // 2 MB
    u16* Vt  = Kbf + rows * D_HEAD;                   // 2 MB (per-batch transposed [b][h][t])
    unsigned* Wpk = (unsigned*)(Vt + rows * D_HEAD);  // 384 KB
    u16* Po16 = (u16*)(Wpk + 128 * 192 * 4);          // SPLIT*16384*64 bf16 = 16 MB
    float* Pl = (float*)(Po16 + (size_t)SPLIT * rows * D_HEAD);  // 512 KB

    hipLaunchKernelGGL(packw_kernel, dim3(96), dim3(256), 0, stream,
                       Wq, Wk, Wv, Wpk);
    hipLaunchKernelGGL(qkv_kernel, dim3(rows / 32), dim3(256), 0, stream,
                       x, Wpk, Qbf, Kbf, Vt);
    hipLaunchKernelGGL(attn_kernel, dim3(512), dim3(256), 0, stream,
                       Qbf, Kbf, Vt, Po16, Pl);
    hipLaunchKernelGGL(reduce_kernel, dim3(NB * 256), dim3(64 * 4), 0, stream,
                       Po16, Pl, out);
}